// Round 3
// baseline (2532.069 us; speedup 1.0000x reference)
//
#include <hip/hip_runtime.h>

#define F_IN  128
#define F_HID 64
#define F_OUT 40
#define BSZ   512          // nodes per bucket
#define BSH   9            // log2(BSZ)
#define CAP   24576        // bucket region capacity (mean 16.3K, sigma 128 -> +64 sigma)

// ---------------- partition edges into destination buckets ----------------
__global__ void k_partition(const int* __restrict__ row, const int* __restrict__ col,
                            int E, int nb, int* __restrict__ gcur,
                            unsigned* __restrict__ bbuf) {
    __shared__ int hist[256];
    __shared__ int cur[256];
    int t = threadIdx.x;
    hist[t] = 0;
    __syncthreads();
    int chunk = (E + gridDim.x - 1) / gridDim.x;
    int e0 = blockIdx.x * chunk;
    int e1 = min(E, e0 + chunk);
    for (int e = e0 + t; e < e1; e += 256)
        atomicAdd(&hist[col[e] >> BSH], 1);
    __syncthreads();
    if (t < nb) cur[t] = t * CAP + atomicAdd(&gcur[t], hist[t]);
    __syncthreads();
    for (int e = e0 + t; e < e1; e += 256) {
        int c = col[e];
        int b = c >> BSH;
        int pos = atomicAdd(&cur[b], 1);
        if (pos < (b + 1) * CAP)   // defensive: never write out of region
            bbuf[pos] = ((unsigned)row[e] << BSH) | (unsigned)(c & (BSZ - 1));
    }
}

// ---------------- per-bucket degree count -> dinv ----------------
__global__ void k_count(const unsigned* __restrict__ bbuf, const int* __restrict__ gcur,
                        float* __restrict__ dinv, int n) {
    __shared__ int cnt[BSZ];
    int b = blockIdx.x, t = threadIdx.x;
    cnt[t] = 0; cnt[t + 256] = 0;
    __syncthreads();
    int nE = gcur[b];
    int base = b * CAP;
    for (int i = t; i < nE; i += 256)
        atomicAdd(&cnt[bbuf[base + i] & (BSZ - 1)], 1);
    __syncthreads();
    for (int i = t; i < BSZ; i += 256) {
        int node = b * BSZ + i;
        if (node < n) dinv[node] = rsqrtf((float)cnt[i] + 1.0f);
    }
}

// ---------------- layer 1 linear: h1s = dinv * (x @ W1) ----------------
__global__ void k_lin1(const float* __restrict__ x, const float* __restrict__ W1,
                       const float* __restrict__ dinv,
                       float* __restrict__ h1s, int n) {
    __shared__ float Ws[F_IN * F_HID];   // 32 KB
    __shared__ float xs[8][F_IN];        // 4 KB
    int t = threadIdx.x;
    for (int i = t; i < F_IN * F_HID; i += 256) Ws[i] = W1[i];
    int node0 = blockIdx.x * 8;
    for (int i = t; i < 8 * F_IN; i += 256) {
        int nd = node0 + (i >> 7);
        xs[i >> 7][i & 127] = (nd < n) ? x[nd * F_IN + (i & 127)] : 0.f;
    }
    __syncthreads();
    int local = t >> 5;
    int j0 = t & 31;
    float acc0 = 0.f, acc1 = 0.f;
#pragma unroll 8
    for (int k = 0; k < F_IN; ++k) {
        float xv = xs[local][k];
        acc0 = fmaf(xv, Ws[k * F_HID + j0], acc0);
        acc1 = fmaf(xv, Ws[k * F_HID + j0 + 32], acc1);
    }
    int nd = node0 + local;
    if (nd < n) {
        float s = dinv[nd];
        h1s[nd * F_HID + j0]      = acc0 * s;
        h1s[nd * F_HID + j0 + 32] = acc1 * s;
    }
}

// ---------------- layer-1 aggregation (LDS acc) + relu + fused W2 GEMM ----------------
// one block per bucket, 1024 threads = 16 waves
__global__ void __launch_bounds__(1024)
k_agg1_lin2(const float* __restrict__ h1s, const unsigned* __restrict__ bbuf,
            const int* __restrict__ gcur, const float* __restrict__ dinv,
            const float* __restrict__ b1, const float* __restrict__ W2,
            float* __restrict__ h2s, int n) {
    __shared__ float acc[BSZ * F_HID];   // 128 KB
    __shared__ float W2s[F_HID * F_OUT]; // 10 KB
    __shared__ float b1s[F_HID];
    int b = blockIdx.x, t = threadIdx.x;
    int node0 = b * BSZ;
    // seed with self-loop contribution (h1s already dinv-scaled)
    for (int i = t; i < BSZ * F_HID; i += 1024) {
        int node = node0 + (i >> 6);
        acc[i] = (node < n) ? h1s[node * F_HID + (i & 63)] : 0.f;
    }
    for (int i = t; i < F_HID * F_OUT; i += 1024) W2s[i] = W2[i];
    if (t < F_HID) b1s[t] = b1[t];
    __syncthreads();

    int nE = gcur[b];
    int base = b * CAP;
    int w = t >> 6, l = t & 63;
    for (int e0 = w * 64; e0 < nE; e0 += 1024) {
        unsigned u = (e0 + l < nE) ? bbuf[base + e0 + l] : 0u;
        int cnt = min(64, nE - e0);
        int j = 0;
        for (; j + 4 <= cnt; j += 4) {
            unsigned u0 = __shfl(u, j),     u1 = __shfl(u, j + 1);
            unsigned u2 = __shfl(u, j + 2), u3 = __shfl(u, j + 3);
            float v0 = h1s[(u0 >> BSH) * F_HID + l];
            float v1 = h1s[(u1 >> BSH) * F_HID + l];
            float v2 = h1s[(u2 >> BSH) * F_HID + l];
            float v3 = h1s[(u3 >> BSH) * F_HID + l];
            atomicAdd(&acc[(u0 & (BSZ - 1)) * F_HID + l], v0);
            atomicAdd(&acc[(u1 & (BSZ - 1)) * F_HID + l], v1);
            atomicAdd(&acc[(u2 & (BSZ - 1)) * F_HID + l], v2);
            atomicAdd(&acc[(u3 & (BSZ - 1)) * F_HID + l], v3);
        }
        for (; j < cnt; ++j) {
            unsigned uj = __shfl(u, j);
            atomicAdd(&acc[(uj & (BSZ - 1)) * F_HID + l], h1s[(uj >> BSH) * F_HID + l]);
        }
    }
    __syncthreads();
    // acc -> z1 = relu(acc*dinv + b1), in place
    for (int i = t; i < BSZ * F_HID; i += 1024) {
        int node = node0 + (i >> 6);
        if (node < n) {
            float v = fmaf(acc[i], dinv[node], b1s[i & 63]);
            acc[i] = v > 0.f ? v : 0.f;
        }
    }
    __syncthreads();
    // h2s = dinv * (z1 @ W2)
    for (int o = t; o < BSZ * F_OUT; o += 1024) {
        int nl = o / F_OUT, j = o % F_OUT;
        int node = node0 + nl;
        if (node < n) {
            float s = 0.f;
#pragma unroll
            for (int k = 0; k < F_HID; ++k)
                s = fmaf(acc[nl * F_HID + k], W2s[k * F_OUT + j], s);
            h2s[node * F_OUT + j] = s * dinv[node];
        }
    }
}

// ---------------- layer-2 aggregation (LDS acc) + fused log_softmax ----------------
__global__ void __launch_bounds__(1024)
k_agg2_sm(const float* __restrict__ h2s, const unsigned* __restrict__ bbuf,
          const int* __restrict__ gcur, const float* __restrict__ dinv,
          const float* __restrict__ b2, float* __restrict__ out, int n) {
    __shared__ float acc[BSZ * F_OUT];   // 80 KB
    __shared__ float b2s[F_OUT];
    int b = blockIdx.x, t = threadIdx.x;
    int node0 = b * BSZ;
    for (int i = t; i < BSZ * F_OUT; i += 1024) {
        int node = node0 + i / F_OUT;
        acc[i] = (node < n) ? h2s[node0 * F_OUT + i] : 0.f;  // contiguous seed
    }
    if (t < F_OUT) b2s[t] = b2[t];
    __syncthreads();

    int nE = gcur[b];
    int base = b * CAP;
    int w = t >> 6, l = t & 63;
    for (int e0 = w * 64; e0 < nE; e0 += 1024) {
        unsigned u = (e0 + l < nE) ? bbuf[base + e0 + l] : 0u;
        int cnt = min(64, nE - e0);
        int j = 0;
        for (; j + 4 <= cnt; j += 4) {
            unsigned u0 = __shfl(u, j),     u1 = __shfl(u, j + 1);
            unsigned u2 = __shfl(u, j + 2), u3 = __shfl(u, j + 3);
            if (l < F_OUT) {
                float v0 = h2s[(u0 >> BSH) * F_OUT + l];
                float v1 = h2s[(u1 >> BSH) * F_OUT + l];
                float v2 = h2s[(u2 >> BSH) * F_OUT + l];
                float v3 = h2s[(u3 >> BSH) * F_OUT + l];
                atomicAdd(&acc[(u0 & (BSZ - 1)) * F_OUT + l], v0);
                atomicAdd(&acc[(u1 & (BSZ - 1)) * F_OUT + l], v1);
                atomicAdd(&acc[(u2 & (BSZ - 1)) * F_OUT + l], v2);
                atomicAdd(&acc[(u3 & (BSZ - 1)) * F_OUT + l], v3);
            }
        }
        for (; j < cnt; ++j) {
            unsigned uj = __shfl(u, j);
            if (l < F_OUT)
                atomicAdd(&acc[(uj & (BSZ - 1)) * F_OUT + l],
                          h2s[(uj >> BSH) * F_OUT + l]);
        }
    }
    __syncthreads();
    // log_softmax per row, one wave per row
    for (int r = w; r < BSZ; r += 16) {
        int node = node0 + r;
        if (node >= n) continue;
        float dv = dinv[node];
        float v = (l < F_OUT) ? fmaf(acc[r * F_OUT + l], dv, b2s[l]) : -1e30f;
        float m = v;
#pragma unroll
        for (int off = 32; off > 0; off >>= 1) m = fmaxf(m, __shfl_xor(m, off));
        float ex = (l < F_OUT) ? expf(v - m) : 0.f;
        float s = ex;
#pragma unroll
        for (int off = 32; off > 0; off >>= 1) s += __shfl_xor(s, off);
        if (l < F_OUT) out[node * F_OUT + l] = v - m - logf(s);
    }
}

extern "C" void kernel_launch(void* const* d_in, const int* in_sizes, int n_in,
                              void* d_out, int out_size, void* d_ws, size_t ws_size,
                              hipStream_t stream) {
    const float* x  = (const float*)d_in[0];
    const int*   ei = (const int*)d_in[1];
    const float* W1 = (const float*)d_in[2];
    const float* b1 = (const float*)d_in[3];
    const float* W2 = (const float*)d_in[4];
    const float* b2 = (const float*)d_in[5];
    float* out = (float*)d_out;

    const int n = in_sizes[0] / F_IN;
    const int E = in_sizes[1] / 2;
    const int* row = ei;
    const int* col = ei + E;
    const int nb = (n + BSZ - 1) / BSZ;

    // workspace layout
    char* p = (char*)d_ws;
    float*    dinv = (float*)p;     p += (size_t)n * 4;
    float*    h1s  = (float*)p;     p += (size_t)n * F_HID * 4;
    float*    h2s  = (float*)p;     p += (size_t)n * F_OUT * 4;
    int*      gcur = (int*)p;       p += 256 * 4;
    unsigned* bbuf = (unsigned*)p;  p += (size_t)nb * CAP * 4;

    hipMemsetAsync(gcur, 0, nb * 4, stream);
    k_partition<<<640, 256, 0, stream>>>(row, col, E, nb, gcur, bbuf);
    k_count<<<nb, 256, 0, stream>>>(bbuf, gcur, dinv, n);
    k_lin1<<<(n + 7) / 8, 256, 0, stream>>>(x, W1, dinv, h1s, n);
    k_agg1_lin2<<<nb, 1024, 0, stream>>>(h1s, bbuf, gcur, dinv, b1, W2, h2s, n);
    k_agg2_sm<<<nb, 1024, 0, stream>>>(h2s, bbuf, gcur, dinv, b2, out, n);
}

// Round 4
// 375.188 us; speedup vs baseline: 6.7488x; 6.7488x over previous
//
#include <hip/hip_runtime.h>

#define F_IN  128
#define F_HID 64
#define F_OUT 40
#define BSZ   512          // nodes per bucket
#define BSH   9            // log2(BSZ)
#define CAP   24576        // bucket region capacity (mean 16.3K, sigma ~128 -> +64 sigma)

// ---------------- partition edges into destination buckets ----------------
__global__ void k_partition(const int* __restrict__ row, const int* __restrict__ col,
                            int E, int nb, int* __restrict__ gcur,
                            unsigned* __restrict__ bbuf) {
    __shared__ int hist[256];
    __shared__ int cur[256];
    int t = threadIdx.x;
    hist[t] = 0;
    __syncthreads();
    int chunk = (E + gridDim.x - 1) / gridDim.x;
    int e0 = blockIdx.x * chunk;
    int e1 = min(E, e0 + chunk);
    for (int e = e0 + t; e < e1; e += 256)
        atomicAdd(&hist[col[e] >> BSH], 1);
    __syncthreads();
    if (t < nb) cur[t] = t * CAP + atomicAdd(&gcur[t], hist[t]);
    __syncthreads();
    for (int e = e0 + t; e < e1; e += 256) {
        int c = col[e];
        int b = c >> BSH;
        int pos = atomicAdd(&cur[b], 1);
        if (pos < (b + 1) * CAP)
            bbuf[pos] = ((unsigned)row[e] << BSH) | (unsigned)(c & (BSZ - 1));
    }
}

// ---------------- per-bucket counting sort -> bucket-relative CSR ----------------
// one block per bucket; payload cached in LDS; srow writes stay inside the
// bucket's contiguous 96KB window (L2 write-combines).
__global__ void __launch_bounds__(1024)
k_csr(const unsigned* __restrict__ bbuf, const int* __restrict__ gcur,
      int* __restrict__ beg, int* __restrict__ deg, float* __restrict__ dinv,
      int* __restrict__ srow, int n) {
    __shared__ unsigned pay[CAP];   // 96 KB
    __shared__ int cnt[BSZ];
    __shared__ int cur[BSZ];
    int b = blockIdx.x, t = threadIdx.x;
    int nE = min(gcur[b], CAP);
    int base = b * CAP;
    for (int i = t; i < BSZ; i += 1024) cnt[i] = 0;
    __syncthreads();
    for (int i = t; i < nE; i += 1024) {
        unsigned u = bbuf[base + i];
        pay[i] = u;
        atomicAdd(&cnt[u & (BSZ - 1)], 1);
    }
    __syncthreads();
    // Hillis-Steele inclusive scan of cnt into cur
    if (t < BSZ) cur[t] = cnt[t];
    __syncthreads();
    for (int off = 1; off < BSZ; off <<= 1) {
        int add = (t < BSZ && t >= off) ? cur[t - off] : 0;
        __syncthreads();
        if (t < BSZ) cur[t] += add;
        __syncthreads();
    }
    int node0 = b * BSZ;
    if (t < BSZ) {
        int ex = cur[t] - cnt[t];        // exclusive
        int node = node0 + t;
        if (node < n) {
            beg[node] = base + ex;
            deg[node] = cnt[t];
            dinv[node] = rsqrtf((float)cnt[t] + 1.0f);   // +1 self-loop
        }
        cur[t] = ex;                     // reuse as cursor
    }
    __syncthreads();
    for (int i = t; i < nE; i += 1024) {
        unsigned u = pay[i];
        int pos = atomicAdd(&cur[u & (BSZ - 1)], 1);
        srow[base + pos] = (int)(u >> BSH);
    }
}

// ---------------- layer 1 linear: h1s = dinv * (x @ W1) ----------------
__global__ void k_lin1(const float* __restrict__ x, const float* __restrict__ W1,
                       const float* __restrict__ dinv,
                       float* __restrict__ h1s, int n) {
    __shared__ float Ws[F_IN * F_HID];   // 32 KB
    __shared__ float xs[8][F_IN];        // 4 KB
    int t = threadIdx.x;
    for (int i = t; i < F_IN * F_HID; i += 256) Ws[i] = W1[i];
    int node0 = blockIdx.x * 8;
    for (int i = t; i < 8 * F_IN; i += 256) {
        int nd = node0 + (i >> 7);
        xs[i >> 7][i & 127] = (nd < n) ? x[nd * F_IN + (i & 127)] : 0.f;
    }
    __syncthreads();
    int local = t >> 5;
    int j0 = t & 31;
    float acc0 = 0.f, acc1 = 0.f;
#pragma unroll 8
    for (int k = 0; k < F_IN; ++k) {
        float xv = xs[local][k];
        acc0 = fmaf(xv, Ws[k * F_HID + j0], acc0);
        acc1 = fmaf(xv, Ws[k * F_HID + j0 + 32], acc1);
    }
    int nd = node0 + local;
    if (nd < n) {
        float s = dinv[nd];
        h1s[nd * F_HID + j0]      = acc0 * s;
        h1s[nd * F_HID + j0 + 32] = acc1 * s;
    }
}

// ---------------- layer-1 CSR aggregation + relu + fused W2 GEMM ----------------
// block 256 = 4 waves, one wave per node; z-row staged in LDS for the lin2 dot.
__global__ void k_agg1(const float* __restrict__ h1s, const int* __restrict__ beg,
                       const int* __restrict__ deg, const int* __restrict__ srow,
                       const float* __restrict__ dinv, const float* __restrict__ b1,
                       const float* __restrict__ W2, float* __restrict__ h2s, int n) {
    __shared__ float W2s[F_HID * F_OUT];  // 10 KB
    __shared__ float zrow[4][F_HID];
    int t = threadIdx.x;
    for (int i = t; i < F_HID * F_OUT; i += 256) W2s[i] = W2[i];
    __syncthreads();
    int lane = t & 63, w = t >> 6;
    int node = blockIdx.x * 4 + w;
    if (node >= n) return;
    int bg = beg[node], cnt = deg[node];
    float acc = h1s[node * F_HID + lane];   // self-loop (h1s already dinv-scaled)
    for (int e0 = 0; e0 < cnt; e0 += 64) {
        int m = min(64, cnt - e0);
        int r = (e0 + lane < cnt) ? srow[bg + e0 + lane] : 0;
        int j = 0;
        for (; j + 4 <= m; j += 4) {
            int r0 = __shfl(r, j),     r1 = __shfl(r, j + 1);
            int r2 = __shfl(r, j + 2), r3 = __shfl(r, j + 3);
            acc += h1s[r0 * F_HID + lane] + h1s[r1 * F_HID + lane]
                 + h1s[r2 * F_HID + lane] + h1s[r3 * F_HID + lane];
        }
        for (; j < m; ++j)
            acc += h1s[__shfl(r, j) * F_HID + lane];
    }
    float dv = dinv[node];
    float z = fmaf(acc, dv, b1[lane]);
    z = z > 0.f ? z : 0.f;
    zrow[w][lane] = z;                      // same-wave LDS write->read, in-order DS pipe
    if (lane < F_OUT) {
        float s = 0.f;
#pragma unroll
        for (int k = 0; k < F_HID; ++k)
            s = fmaf(zrow[w][k], W2s[k * F_OUT + lane], s);
        h2s[node * F_OUT + lane] = s * dv;
    }
}

// ---------------- layer-2 CSR aggregation + bias + log_softmax ----------------
__global__ void k_agg2(const float* __restrict__ h2s, const int* __restrict__ beg,
                       const int* __restrict__ deg, const int* __restrict__ srow,
                       const float* __restrict__ dinv, const float* __restrict__ b2,
                       float* __restrict__ out, int n) {
    int t = threadIdx.x, lane = t & 63, w = t >> 6;
    int node = blockIdx.x * 4 + w;
    if (node >= n) return;
    int bg = beg[node], cnt = deg[node];
    float acc = (lane < F_OUT) ? h2s[node * F_OUT + lane] : 0.f;  // self-loop
    for (int e0 = 0; e0 < cnt; e0 += 64) {
        int m = min(64, cnt - e0);
        int r = (e0 + lane < cnt) ? srow[bg + e0 + lane] : 0;
        int j = 0;
        for (; j + 4 <= m; j += 4) {
            int r0 = __shfl(r, j),     r1 = __shfl(r, j + 1);
            int r2 = __shfl(r, j + 2), r3 = __shfl(r, j + 3);
            if (lane < F_OUT)
                acc += h2s[r0 * F_OUT + lane] + h2s[r1 * F_OUT + lane]
                     + h2s[r2 * F_OUT + lane] + h2s[r3 * F_OUT + lane];
        }
        for (; j < m; ++j) {
            int rj = __shfl(r, j);
            if (lane < F_OUT) acc += h2s[rj * F_OUT + lane];
        }
    }
    float v = (lane < F_OUT) ? fmaf(acc, dinv[node], b2[lane]) : -1e30f;
    float mx = v;
#pragma unroll
    for (int off = 32; off > 0; off >>= 1) mx = fmaxf(mx, __shfl_xor(mx, off));
    float ex = (lane < F_OUT) ? expf(v - mx) : 0.f;
    float s = ex;
#pragma unroll
    for (int off = 32; off > 0; off >>= 1) s += __shfl_xor(s, off);
    if (lane < F_OUT) out[node * F_OUT + lane] = v - mx - logf(s);
}

extern "C" void kernel_launch(void* const* d_in, const int* in_sizes, int n_in,
                              void* d_out, int out_size, void* d_ws, size_t ws_size,
                              hipStream_t stream) {
    const float* x  = (const float*)d_in[0];
    const int*   ei = (const int*)d_in[1];
    const float* W1 = (const float*)d_in[2];
    const float* b1 = (const float*)d_in[3];
    const float* W2 = (const float*)d_in[4];
    const float* b2 = (const float*)d_in[5];
    float* out = (float*)d_out;

    const int n = in_sizes[0] / F_IN;
    const int E = in_sizes[1] / 2;
    const int* row = ei;
    const int* col = ei + E;
    const int nb = (n + BSZ - 1) / BSZ;

    // workspace layout
    char* p = (char*)d_ws;
    float*    dinv = (float*)p;     p += (size_t)n * 4;
    float*    h1s  = (float*)p;     p += (size_t)n * F_HID * 4;
    float*    h2s  = (float*)p;     p += (size_t)n * F_OUT * 4;
    int*      beg  = (int*)p;       p += (size_t)n * 4;
    int*      deg  = (int*)p;       p += (size_t)n * 4;
    int*      gcur = (int*)p;       p += 256 * 4;
    unsigned* bbuf = (unsigned*)p;  p += (size_t)nb * CAP * 4;
    int*      srow = (int*)p;       p += (size_t)nb * CAP * 4;

    hipMemsetAsync(gcur, 0, nb * 4, stream);
    k_partition<<<640, 256, 0, stream>>>(row, col, E, nb, gcur, bbuf);
    k_csr<<<nb, 1024, 0, stream>>>(bbuf, gcur, beg, deg, dinv, srow, n);
    k_lin1<<<(n + 7) / 8, 256, 0, stream>>>(x, W1, dinv, h1s, n);
    k_agg1<<<(n + 3) / 4, 256, 0, stream>>>(h1s, beg, deg, srow, dinv, b1, W2, h2s, n);
    k_agg2<<<(n + 3) / 4, 256, 0, stream>>>(h2s, beg, deg, srow, dinv, b2, out, n);
}

// Round 5
// 348.319 us; speedup vs baseline: 7.2694x; 1.0771x over previous
//
#include <hip/hip_runtime.h>

#define F_IN  128
#define F_HID 64
#define F_OUT 40
#define BSZ   512          // nodes per bucket
#define BSH   9            // log2(BSZ)
#define CAP   24576        // bucket region capacity (mean 16.3K, sigma ~128)

// pack two floats as bf16 pair (round-to-nearest-even): low16 = a, high16 = b
static __device__ __forceinline__ unsigned pack_bf16(float a, float b) {
    unsigned ua = __float_as_uint(a);
    unsigned ub = __float_as_uint(b);
    ua = (ua + 0x7fffu + ((ua >> 16) & 1u)) >> 16;
    ub = (ub + 0x7fffu + ((ub >> 16) & 1u)) & 0xffff0000u;
    return ua | ub;
}
static __device__ __forceinline__ float bf_lo(unsigned u) { return __uint_as_float(u << 16); }
static __device__ __forceinline__ float bf_hi(unsigned u) { return __uint_as_float(u & 0xffff0000u); }

// ---------------- partition edges into destination buckets ----------------
__global__ void k_partition(const int* __restrict__ row, const int* __restrict__ col,
                            int E, int nb, int* __restrict__ gcur,
                            unsigned* __restrict__ bbuf) {
    __shared__ int hist[256];
    __shared__ int cur[256];
    int t = threadIdx.x;
    hist[t] = 0;
    __syncthreads();
    int chunk = (E + gridDim.x - 1) / gridDim.x;
    int e0 = blockIdx.x * chunk;
    int e1 = min(E, e0 + chunk);
    for (int e = e0 + t; e < e1; e += 256)
        atomicAdd(&hist[col[e] >> BSH], 1);
    __syncthreads();
    if (t < nb) cur[t] = t * CAP + atomicAdd(&gcur[t], hist[t]);
    __syncthreads();
    for (int e = e0 + t; e < e1; e += 256) {
        int c = col[e];
        int b = c >> BSH;
        int pos = atomicAdd(&cur[b], 1);
        if (pos < (b + 1) * CAP)
            bbuf[pos] = ((unsigned)row[e] << BSH) | (unsigned)(c & (BSZ - 1));
    }
}

// ---------------- per-bucket counting sort -> bucket-relative CSR ----------------
__global__ void __launch_bounds__(1024)
k_csr(const unsigned* __restrict__ bbuf, const int* __restrict__ gcur,
      int* __restrict__ beg, int* __restrict__ deg, float* __restrict__ dinv,
      int* __restrict__ srow, int n) {
    __shared__ unsigned pay[CAP];   // 96 KB
    __shared__ int cnt[BSZ];
    __shared__ int cur[BSZ];
    int b = blockIdx.x, t = threadIdx.x;
    int nE = min(gcur[b], CAP);
    int base = b * CAP;
    for (int i = t; i < BSZ; i += 1024) cnt[i] = 0;
    __syncthreads();
    for (int i = t; i < nE; i += 1024) {
        unsigned u = bbuf[base + i];
        pay[i] = u;
        atomicAdd(&cnt[u & (BSZ - 1)], 1);
    }
    __syncthreads();
    if (t < BSZ) cur[t] = cnt[t];
    __syncthreads();
    for (int off = 1; off < BSZ; off <<= 1) {
        int add = (t < BSZ && t >= off) ? cur[t - off] : 0;
        __syncthreads();
        if (t < BSZ) cur[t] += add;
        __syncthreads();
    }
    int node0 = b * BSZ;
    if (t < BSZ) {
        int ex = cur[t] - cnt[t];
        int node = node0 + t;
        if (node < n) {
            beg[node] = base + ex;
            deg[node] = cnt[t];
            dinv[node] = rsqrtf((float)cnt[t] + 1.0f);
        }
        cur[t] = ex;
    }
    __syncthreads();
    for (int i = t; i < nE; i += 1024) {
        unsigned u = pay[i];
        int pos = atomicAdd(&cur[u & (BSZ - 1)], 1);
        srow[base + pos] = (int)(u >> BSH);
    }
}

// ---------------- layer 1 linear: h1b = bf16( dinv * (x @ W1) ) ----------------
// thread computes adjacent features 2c, 2c+1 so the pair packs into one uint.
__global__ void k_lin1(const float* __restrict__ x, const float* __restrict__ W1,
                       const float* __restrict__ dinv,
                       unsigned* __restrict__ h1b, int n) {
    __shared__ float Ws[F_IN * F_HID];   // 32 KB
    __shared__ float xs[8][F_IN];        // 4 KB
    int t = threadIdx.x;
    for (int i = t; i < F_IN * F_HID; i += 256) Ws[i] = W1[i];
    int node0 = blockIdx.x * 8;
    for (int i = t; i < 8 * F_IN; i += 256) {
        int nd = node0 + (i >> 7);
        xs[i >> 7][i & 127] = (nd < n) ? x[nd * F_IN + (i & 127)] : 0.f;
    }
    __syncthreads();
    int local = t >> 5;
    int c = t & 31;
    float acc0 = 0.f, acc1 = 0.f;
#pragma unroll 8
    for (int k = 0; k < F_IN; ++k) {
        float xv = xs[local][k];
        acc0 = fmaf(xv, Ws[k * F_HID + 2 * c], acc0);
        acc1 = fmaf(xv, Ws[k * F_HID + 2 * c + 1], acc1);
    }
    int nd = node0 + local;
    if (nd < n) {
        float s = dinv[nd];
        h1b[nd * 32 + c] = pack_bf16(acc0 * s, acc1 * s);
    }
}

// ---------------- layer-1 aggregation (2 edges / VMEM) + relu + fused W2 GEMM ----------------
__global__ void k_agg1(const unsigned* __restrict__ h1b, const int* __restrict__ beg,
                       const int* __restrict__ deg, const int* __restrict__ srow,
                       const float* __restrict__ dinv, const float* __restrict__ b1,
                       const float* __restrict__ W2, unsigned* __restrict__ h2b, int n) {
    __shared__ float W2s[F_HID * F_OUT];  // 10 KB
    __shared__ float zrow[4][F_HID];
    int t = threadIdx.x;
    for (int i = t; i < F_HID * F_OUT; i += 256) W2s[i] = W2[i];
    __syncthreads();
    int lane = t & 63, w = t >> 6;
    int half = lane >> 5, c = lane & 31;
    int node = blockIdx.x * 4 + w;
    if (node >= n) return;
    int bg = beg[node], cnt = deg[node];
    float acc0 = 0.f, acc1 = 0.f;
    for (int e0 = 0; e0 < cnt; e0 += 64) {
        int m = min(64, cnt - e0);
        int r = (e0 + lane < cnt) ? srow[bg + e0 + lane] : 0;
        int j = 0;
        for (; j + 4 <= m; j += 4) {          // 4 edges, 2 VMEM
            int ra = __shfl(r, j + half);
            int rb = __shfl(r, j + 2 + half);
            unsigned ua = h1b[ra * 32 + c];
            unsigned ub = h1b[rb * 32 + c];
            acc0 += bf_lo(ua) + bf_lo(ub);
            acc1 += bf_hi(ua) + bf_hi(ub);
        }
        for (; j + 2 <= m; j += 2) {          // 2 edges, 1 VMEM
            int ra = __shfl(r, j + half);
            unsigned ua = h1b[ra * 32 + c];
            acc0 += bf_lo(ua);
            acc1 += bf_hi(ua);
        }
        if (j < m) {                          // odd tail: half 0 only
            int ra = __shfl(r, m - 1);
            unsigned ua = (half == 0) ? h1b[ra * 32 + c] : 0u;
            acc0 += bf_lo(ua);
            acc1 += bf_hi(ua);
        }
    }
    acc0 += __shfl_xor(acc0, 32);
    acc1 += __shfl_xor(acc1, 32);
    float dv = dinv[node];
    unsigned us = h1b[node * 32 + c];         // self-loop (already dinv-scaled)
    if (half == 0) {
        float z0 = fmaf(acc0 + bf_lo(us), dv, b1[2 * c]);
        float z1 = fmaf(acc1 + bf_hi(us), dv, b1[2 * c + 1]);
        zrow[w][2 * c]     = z0 > 0.f ? z0 : 0.f;
        zrow[w][2 * c + 1] = z1 > 0.f ? z1 : 0.f;
    }
    // same-wave DS write->read, in-order
    float s = 0.f;
    if (lane < F_OUT) {
#pragma unroll
        for (int k = 0; k < F_HID; ++k)
            s = fmaf(zrow[w][k], W2s[k * F_OUT + lane], s);
        s *= dv;
    }
    float partner = __shfl_xor(s, 1);
    if (lane < F_OUT && (lane & 1) == 0)
        h2b[node * 20 + (lane >> 1)] = pack_bf16(s, partner);
}

// ---------------- layer-2 aggregation (2 edges / VMEM) + bias + log_softmax ----------------
__global__ void k_agg2(const unsigned* __restrict__ h2b, const int* __restrict__ beg,
                       const int* __restrict__ deg, const int* __restrict__ srow,
                       const float* __restrict__ dinv, const float* __restrict__ b2,
                       float* __restrict__ out, int n) {
    int t = threadIdx.x, lane = t & 63, w = t >> 6;
    int half = lane >> 5, c = lane & 31;
    bool act = c < 20;
    int node = blockIdx.x * 4 + w;
    if (node >= n) return;
    int bg = beg[node], cnt = deg[node];
    float acc0 = 0.f, acc1 = 0.f;
    for (int e0 = 0; e0 < cnt; e0 += 64) {
        int m = min(64, cnt - e0);
        int r = (e0 + lane < cnt) ? srow[bg + e0 + lane] : 0;
        int j = 0;
        for (; j + 4 <= m; j += 4) {
            int ra = __shfl(r, j + half);
            int rb = __shfl(r, j + 2 + half);
            unsigned ua = act ? h2b[ra * 20 + c] : 0u;
            unsigned ub = act ? h2b[rb * 20 + c] : 0u;
            acc0 += bf_lo(ua) + bf_lo(ub);
            acc1 += bf_hi(ua) + bf_hi(ub);
        }
        for (; j + 2 <= m; j += 2) {
            int ra = __shfl(r, j + half);
            unsigned ua = act ? h2b[ra * 20 + c] : 0u;
            acc0 += bf_lo(ua);
            acc1 += bf_hi(ua);
        }
        if (j < m) {
            int ra = __shfl(r, m - 1);
            unsigned ua = (act && half == 0) ? h2b[ra * 20 + c] : 0u;
            acc0 += bf_lo(ua);
            acc1 += bf_hi(ua);
        }
    }
    acc0 += __shfl_xor(acc0, 32);
    acc1 += __shfl_xor(acc1, 32);
    float dv = dinv[node];
    unsigned us = act ? h2b[node * 20 + c] : 0u;   // self-loop
    float v0 = act ? fmaf(acc0 + bf_lo(us), dv, b2[2 * c])     : -1e30f;
    float v1 = act ? fmaf(acc1 + bf_hi(us), dv, b2[2 * c + 1]) : -1e30f;
    float mx = fmaxf(v0, v1);
#pragma unroll
    for (int off = 16; off > 0; off >>= 1) mx = fmaxf(mx, __shfl_xor(mx, off));
    float ex = act ? (expf(v0 - mx) + expf(v1 - mx)) : 0.f;
#pragma unroll
    for (int off = 16; off > 0; off >>= 1) ex += __shfl_xor(ex, off);
    float lg = logf(ex);
    if (act && half == 0) {
        out[node * F_OUT + 2 * c]     = v0 - mx - lg;
        out[node * F_OUT + 2 * c + 1] = v1 - mx - lg;
    }
}

extern "C" void kernel_launch(void* const* d_in, const int* in_sizes, int n_in,
                              void* d_out, int out_size, void* d_ws, size_t ws_size,
                              hipStream_t stream) {
    const float* x  = (const float*)d_in[0];
    const int*   ei = (const int*)d_in[1];
    const float* W1 = (const float*)d_in[2];
    const float* b1 = (const float*)d_in[3];
    const float* W2 = (const float*)d_in[4];
    const float* b2 = (const float*)d_in[5];
    float* out = (float*)d_out;

    const int n = in_sizes[0] / F_IN;
    const int E = in_sizes[1] / 2;
    const int* row = ei;
    const int* col = ei + E;
    const int nb = (n + BSZ - 1) / BSZ;

    char* p = (char*)d_ws;
    float*    dinv = (float*)p;     p += (size_t)n * 4;
    unsigned* h1b  = (unsigned*)p;  p += (size_t)n * 32 * 4;
    unsigned* h2b  = (unsigned*)p;  p += (size_t)n * 20 * 4;
    int*      beg  = (int*)p;       p += (size_t)n * 4;
    int*      deg  = (int*)p;       p += (size_t)n * 4;
    int*      gcur = (int*)p;       p += 256 * 4;
    unsigned* bbuf = (unsigned*)p;  p += (size_t)nb * CAP * 4;
    int*      srow = (int*)p;       p += (size_t)nb * CAP * 4;

    hipMemsetAsync(gcur, 0, nb * 4, stream);
    k_partition<<<640, 256, 0, stream>>>(row, col, E, nb, gcur, bbuf);
    k_csr<<<nb, 1024, 0, stream>>>(bbuf, gcur, beg, deg, dinv, srow, n);
    k_lin1<<<(n + 7) / 8, 256, 0, stream>>>(x, W1, dinv, h1b, n);
    k_agg1<<<(n + 3) / 4, 256, 0, stream>>>(h1b, beg, deg, srow, dinv, b1, W2, h2b, n);
    k_agg2<<<(n + 3) / 4, 256, 0, stream>>>(h2b, beg, deg, srow, dinv, b2, out, n);
}